// Round 11
// baseline (49.423 us; speedup 1.0000x reference)
//
#include <hip/hip_runtime.h>

#define HD 1024           // hidden dim D
#define D4 (HD/4)         // float4s per row = 256
#define GBLK 256          // phase-1 blocks: 1/CU, 1MB sequential stream each
#define BT 512            // 512 threads = 8 waves/CU (A/B vs 256 at same G)

typedef float floatx4 __attribute__((ext_vector_type(4)));  // nontemporal-OK

// Kernel 1: partial column-reduction. Block b owns rows [b*rpb,(b+1)*rpb)
// (1 MB strictly sequential). 512 threads: half = t>>8 picks row parity,
// col = t&255 picks float4 column. Per iter the block covers 8 rows; each
// thread issues 4 float4 loads -> same 32KB/CU in flight but 8 waves/CU
// issuing (vs 4), probing whether the ~10 B/cyc/CU read rate is a hard cap.
// Each half-block writes its parity partial -> partials[2b+half].
__global__ void __launch_bounds__(BT) partial_reduce(
        const float* __restrict__ past,   // [N, HD]
        const float* __restrict__ grad,   // [N]
        float* __restrict__ partials,     // [2G, HD]
        int N, int G) {
    const int b = blockIdx.x;
    const int t = threadIdx.x;            // 0..511
    const int col = t & 255;              // float4 index within row
    const int half = t >> 8;              // 0: even rows, 1: odd rows
    const float4* past4 = (const float4*)past;
    const int rpb = N / G;                // rows per block (256)
    const int r0 = b * rpb;
    const int rend = r0 + rpb;
    float4 a0 = make_float4(0.f, 0.f, 0.f, 0.f);
    float4 a1 = make_float4(0.f, 0.f, 0.f, 0.f);
    float4 a2 = make_float4(0.f, 0.f, 0.f, 0.f);
    float4 a3 = make_float4(0.f, 0.f, 0.f, 0.f);
    for (int r = r0; r + 8 <= rend; r += 8) {
        const int rr = r + half;
        const float g0 = grad[rr + 0];    // wave-uniform (half fixed per wave)
        const float g1 = grad[rr + 2];
        const float g2 = grad[rr + 4];
        const float g3 = grad[rr + 6];
        const float4 v0 = past4[(size_t)(rr + 0) * D4 + col];  // coalesced
        const float4 v1 = past4[(size_t)(rr + 2) * D4 + col];
        const float4 v2 = past4[(size_t)(rr + 4) * D4 + col];
        const float4 v3 = past4[(size_t)(rr + 6) * D4 + col];
        a0.x += g0 * v0.x; a0.y += g0 * v0.y; a0.z += g0 * v0.z; a0.w += g0 * v0.w;
        a1.x += g1 * v1.x; a1.y += g1 * v1.y; a1.z += g1 * v1.z; a1.w += g1 * v1.w;
        a2.x += g2 * v2.x; a2.y += g2 * v2.y; a2.z += g2 * v2.z; a2.w += g2 * v2.w;
        a3.x += g3 * v3.x; a3.y += g3 * v3.y; a3.z += g3 * v3.z; a3.w += g3 * v3.w;
    }
    a0.x += a1.x + a2.x + a3.x;
    a0.y += a1.y + a2.y + a3.y;
    a0.z += a1.z + a2.z + a3.z;
    a0.w += a1.w + a2.w + a3.w;
    ((float4*)partials)[(size_t)(2 * b + half) * D4 + col] = a0;  // coalesced
}

// Kernel 2: fused final-reduce + outer product over G2 = 2G partial rows.
// out written with non-temporal stores (written once, never re-read by us).
__global__ void __launch_bounds__(256) finish_outer(
        const float* __restrict__ partials,  // [G2, HD]
        const float* __restrict__ cur,       // [HD]
        float* __restrict__ out,             // [HD, HD]
        int G2) {
    __shared__ float lds[16];
    __shared__ float wrow[4];
    const int t = threadIdx.x;               // 0..255
    const int R = blockIdx.x * 4;            // first output row of this block
    const int c = R + (t & 3);               // partials column this lane sums
    float acc = 0.f;
    for (int g = (t >> 2); g < G2; g += 64)
        acc += partials[(size_t)g * HD + c]; // L2/L3-resident
    acc += __shfl_xor(acc, 4);
    acc += __shfl_xor(acc, 8);
    acc += __shfl_xor(acc, 16);
    acc += __shfl_xor(acc, 32);
    const int lane = t & 63, wave = t >> 6;
    if (lane < 4) lds[wave * 4 + lane] = acc;
    __syncthreads();
    if (t < 4) wrow[t] = lds[t] + lds[4 + t] + lds[8 + t] + lds[12 + t];
    __syncthreads();
    const float4 cv = ((const float4*)cur)[t];          // L2-hot
    #pragma unroll
    for (int j = 0; j < 4; ++j) {
        const float w = wrow[j];
        floatx4 o;
        o.x = w * cv.x; o.y = w * cv.y; o.z = w * cv.z; o.w = w * cv.w;
        __builtin_nontemporal_store(o, (floatx4*)out + (size_t)(R + j) * D4 + t);
    }
}

extern "C" void kernel_launch(void* const* d_in, const int* in_sizes, int n_in,
                              void* d_out, int out_size, void* d_ws, size_t ws_size,
                              hipStream_t stream) {
    const float* past = (const float*)d_in[0];   // [N, 1024] fp32
    const float* cur  = (const float*)d_in[1];   // [1024] fp32
    const float* grad = (const float*)d_in[2];   // [N] fp32
    float* out = (float*)d_out;                  // [1024, 1024] fp32
    const int N = in_sizes[2];                   // 65536

    float* partials = (float*)d_ws;              // [2G, 1024] floats (2 MB)

    int G = GBLK;                                // 1 block/CU, 8 waves/CU
    const size_t avail_floats = ws_size / sizeof(float);
    if ((size_t)(2 * G) * HD > avail_floats) {
        G = (int)(avail_floats / (2 * HD));
        if (G < 1) G = 1;
    }

    partial_reduce<<<G, BT, 0, stream>>>(past, grad, partials, N, G);
    finish_outer<<<HD / 4, 256, 0, stream>>>(partials, cur, out, 2 * G);
}